// Round 6
// baseline (283.748 us; speedup 1.0000x reference)
//
#include <hip/hip_runtime.h>

// QuantizedBottleneck via i8 MFMA implicit GEMM. Exact integer math.
//   prep : pack all MFMA A-fragments (w1/w2/w3 -> i8) into d_ws
//   conv1: 1x1 256->64 + bn1 -> t1 [n][64] i8   (dwordx4 staging, reg dbuf)
//   conv2: 3x3 64->64 pad1 + bn2 -> t2 [n][64] i8 (padded-col LDS slab)
//   conv3: 1x1 64->256 + bn3 + residual add (LDS LUTs) -> out int32
// t1/t2 hold (q - next_zin) so zero-padding == zero bytes.
// Requant uses the exact single-shift identity:
//   ((p+nudge)>>31 + 2^(s-1)) >> s  ==  (p + nudge + 2^(30+s)) >> (31+s)
// NOTE: R5 failed post-timing (call#1 right, later calls identically wrong)
// with __builtin_nontemporal_* + launch_bounds(256,6) in conv3; both removed
// here — NT cache-bypass interacting with the harness's per-replay restore
// blit is the prime suspect. No other changes vs R5.
// MFMA 16x16x64_i8: A[m=lane&15][k=(lane>>4)*16+j], B[k][n=lane&15],
// C/D: col=lane&15, row=(lane>>4)*4+reg.

typedef int v4i __attribute__((ext_vector_type(4)));

#define BATCH 32
#define CIN 256
#define CMID 64
#define HW 3136
#define W56 56

#define T1_BYTES ((size_t)BATCH * HW * CMID)
#define WP_BYTES ((size_t)68 * 64 * 16)

// fast exact requant: prod=acc*M0; add sign-dependent combined nudge; one shift
__device__ __forceinline__ int requant_f(int acc, int M0, long long pAdd,
                                         long long nAdd, int tSh, int zout) {
    long long prod = (long long)acc * (long long)M0;
    long long add = (prod >= 0) ? pAdd : nAdd;
    int v = (int)((prod + add) >> tSh) + zout;
    return v < 0 ? 0 : (v > 255 ? 255 : v);
}

__device__ __forceinline__ v4i pack16f(const float* src, int stride) {
    v4i r;
#pragma unroll
    for (int d = 0; d < 4; ++d) {
        unsigned int u = 0;
#pragma unroll
        for (int by = 0; by < 4; ++by) {
            int v = (int)src[(d * 4 + by) * stride];
            u |= ((unsigned int)(v & 255)) << (8 * by);
        }
        r[d] = (int)u;
    }
    return r;
}

// -------- prep: fragsets w1 [0,16), w2 [16,52), w3 [52,68) -------------------
__global__ __launch_bounds__(256) void k_prep(
    const float* __restrict__ w1, const float* __restrict__ w2,
    const float* __restrict__ w3, v4i* __restrict__ wp)
{
    int id = blockIdx.x * 256 + threadIdx.x;
    int fid = id >> 6, lane = id & 63;
    if (fid >= 68) return;
    int col = lane & 15, ci0 = (lane >> 4) * 16;
    const float* src;
    int stride;
    if (fid < 16) {
        int wv = fid >> 2, ks = fid & 3;
        src = w1 + (size_t)(wv * 16 + col) * 256 + ks * 64 + ci0;
        stride = 1;
    } else if (fid < 52) {
        int i = fid - 16, wv = i / 9, t = i - wv * 9;
        src = w2 + ((size_t)(wv * 16 + col) * 64 + ci0) * 9 + t;
        stride = 9;
    } else {
        int s = fid - 52;
        src = w3 + (size_t)(s * 16 + col) * 64 + ci0;
        stride = 1;
    }
    wp[fid * 64 + lane] = pack16f(src, stride);
}

// -------- conv1: 1x1 256->64 + bn1 -> t1 ------------------------------------
// grid (28, 32): row-pair x batch; tile = 112 px. dwordx4 staging, reg dbuf.
__global__ __launch_bounds__(256, 4) void k_conv1(
    const int* __restrict__ x, const v4i* __restrict__ wp1,
    const float* __restrict__ bn_w, const float* __restrict__ bn_b,
    const int* __restrict__ conv_zin, const int* __restrict__ conv_m0,
    const int* __restrict__ conv_shift, const int* __restrict__ conv_zout,
    const int* __restrict__ bn_m0, const int* __restrict__ bn_shift,
    const int* __restrict__ bn_zout, signed char* __restrict__ t1)
{
    __shared__ v4i sm[560];                        // 112 px x 80 B
    const int tid = threadIdx.x, lane = tid & 63, wv = tid >> 6;
    const int col = lane & 15, koff = lane >> 4;
    const int b = blockIdx.y;
    const int hw0 = blockIdx.x * 112;
    const int co0 = wv * 16;

    v4i a[4];
#pragma unroll
    for (int ks = 0; ks < 4; ++ks) a[ks] = wp1[(wv * 4 + ks) * 64 + lane];

    const int cg = tid & 7, q = tid >> 3;
    const bool act = q < 28;
    const int zin = conv_zin[0];
    const int* xbase = x + (size_t)b * CIN * HW + hw0 + 4 * q;

    v4i xa[8], xa2[8];
    if (act) {
#pragma unroll
        for (int j = 0; j < 8; ++j)
            xa[j] = *(const v4i*)(xbase + (size_t)(cg * 8 + j) * HW);
    }

    v4i acc[7];
#pragma unroll
    for (int i = 0; i < 7; ++i) acc[i] = (v4i){0, 0, 0, 0};

    unsigned long long* smu = (unsigned long long*)sm;
#pragma unroll
    for (int ks = 0; ks < 4; ++ks) {
        if (ks) __syncthreads();
        if (act) {
#pragma unroll
            for (int p = 0; p < 4; ++p) {
                unsigned int lo = 0, hi = 0;
#pragma unroll
                for (int j = 0; j < 4; ++j) {
                    lo |= ((unsigned int)((xa[j][p] - zin) & 255)) << (8 * j);
                    hi |= ((unsigned int)((xa[j + 4][p] - zin) & 255)) << (8 * j);
                }
                smu[(q * 4 + p) * 10 + cg] = ((unsigned long long)hi << 32) | lo;
            }
        }
        __syncthreads();
        if (ks < 3 && act) {
#pragma unroll
            for (int j = 0; j < 8; ++j)
                xa2[j] = *(const v4i*)(xbase + (size_t)((ks + 1) * 64 + cg * 8 + j) * HW);
        }
#pragma unroll
        for (int nt = 0; nt < 7; ++nt) {
            v4i bf = sm[(nt * 16 + col) * 5 + koff];
            acc[nt] = __builtin_amdgcn_mfma_i32_16x16x64_i8(a[ks], bf, acc[nt], 0, 0, 0);
        }
        if (ks < 3) {
#pragma unroll
            for (int j = 0; j < 8; ++j) xa[j] = xa2[j];
        }
    }

    const int cm0 = conv_m0[0], csh = conv_shift[0], czo = conv_zout[0];
    const int bm0 = bn_m0[0], bsh = bn_shift[0], bzo = bn_zout[0];
    const long long cP = (1LL << 30) + (1LL << (30 + csh));
    const long long cN = (1LL - (1LL << 30)) + (1LL << (30 + csh));
    const long long bP = (1LL << 30) + (1LL << (30 + bsh));
    const long long bN = (1LL - (1LL << 30)) + (1LL << (30 + bsh));
    const int cT = 31 + csh, bT = 31 + bsh;
    const int zin2 = conv_zin[1];
    const int rowb = koff * 4;
    int bw[4], bb[4];
#pragma unroll
    for (int r = 0; r < 4; ++r) {
        bw[r] = (int)bn_w[co0 + rowb + r];
        bb[r] = (int)bn_b[co0 + rowb + r];
    }
#pragma unroll
    for (int nt = 0; nt < 7; ++nt) {
        int n = b * HW + hw0 + nt * 16 + col;
        unsigned int pkd = 0;
#pragma unroll
        for (int r = 0; r < 4; ++r) {
            int qv = requant_f(acc[nt][r], cm0, cP, cN, cT, czo);
            int a2 = (qv - czo) * bw[r] + bb[r];
            int q2 = requant_f(a2, bm0, bP, bN, bT, bzo);
            pkd |= ((unsigned int)((q2 - zin2) & 255)) << (8 * r);
        }
        *(unsigned int*)(t1 + (size_t)n * 64 + co0 + rowb) = pkd;
    }
}

// -------- conv2: 3x3 64->64 pad1 + bn2 -> t2. grid (14,32) ------------------
// padded-col LDS slab: 6 rows x 58 cols (cols 0,57 zero) -> no masking in loop
__global__ __launch_bounds__(256, 4) void k_conv2(
    const signed char* __restrict__ t1, const v4i* __restrict__ wp2,
    const float* __restrict__ bn_w, const float* __restrict__ bn_b,
    const int* __restrict__ conv_zin, const int* __restrict__ conv_m0,
    const int* __restrict__ conv_shift, const int* __restrict__ conv_zout,
    const int* __restrict__ bn_m0, const int* __restrict__ bn_shift,
    const int* __restrict__ bn_zout, signed char* __restrict__ t2)
{
    __shared__ v4i sm[1740];                      // 348 px x 80 B = 27.8 KB
    const int tid = threadIdx.x, lane = tid & 63, wv = tid >> 6;
    const int col = lane & 15, koff = lane >> 4;
    const int b = blockIdx.y;
    const int r0 = blockIdx.x * 4;
    const int co0 = wv * 16;

    v4i a[9];
#pragma unroll
    for (int t = 0; t < 9; ++t) a[t] = wp2[(wv * 9 + t) * 64 + lane];

    const v4i* t1v = (const v4i*)t1;
#pragma unroll
    for (int k = 0; k < 6; ++k) {
        int idx = tid + k * 256;
        if (idx < 1344) {
            int pixl = idx >> 2, part = idx & 3;
            int lrow = pixl / W56, gw = pixl - lrow * W56;
            int grow = r0 - 1 + lrow;
            v4i v = (v4i){0, 0, 0, 0};
            if ((unsigned)grow < 56u)
                v = t1v[((size_t)b * HW + grow * W56 + gw) * 4 + part];
            sm[(lrow * 58 + gw + 1) * 5 + part] = v;
        }
    }
    if (tid < 48) {                               // zero edge columns 0 and 57
        int e = tid >> 2, part = tid & 3;
        int row = e >> 1, side = e & 1;
        sm[(row * 58 + side * 57) * 5 + part] = (v4i){0, 0, 0, 0};
    }
    __syncthreads();

    int basep[14];
#pragma unroll
    for (int nt = 0; nt < 14; ++nt) {
        int pix = nt * 16 + col;
        int orow = pix / W56, wc = pix - orow * W56;
        basep[nt] = (orow * 58 + wc) * 5 + koff;
    }

    v4i acc[14];
#pragma unroll
    for (int i = 0; i < 14; ++i) acc[i] = (v4i){0, 0, 0, 0};

#pragma unroll
    for (int kh = 0; kh < 3; ++kh) {
#pragma unroll
        for (int kw = 0; kw < 3; ++kw) {
            v4i af = a[kh * 3 + kw];
            const int toff = (kh * 58 + kw) * 5;  // immediate ds offset
#pragma unroll
            for (int nt = 0; nt < 14; ++nt) {
                v4i bf = sm[basep[nt] + toff];
                acc[nt] = __builtin_amdgcn_mfma_i32_16x16x64_i8(af, bf, acc[nt], 0, 0, 0);
            }
        }
    }

    const int cm0 = conv_m0[1], csh = conv_shift[1], czo = conv_zout[1];
    const int bm0 = bn_m0[1], bsh = bn_shift[1], bzo = bn_zout[1];
    const long long cP = (1LL << 30) + (1LL << (30 + csh));
    const long long cN = (1LL - (1LL << 30)) + (1LL << (30 + csh));
    const long long bP = (1LL << 30) + (1LL << (30 + bsh));
    const long long bN = (1LL - (1LL << 30)) + (1LL << (30 + bsh));
    const int cT = 31 + csh, bT = 31 + bsh;
    const int zin3 = conv_zin[2];
    const int rowb = koff * 4;
    int bw[4], bb[4];
#pragma unroll
    for (int r = 0; r < 4; ++r) {
        bw[r] = (int)bn_w[co0 + rowb + r];
        bb[r] = (int)bn_b[co0 + rowb + r];
    }
#pragma unroll
    for (int nt = 0; nt < 14; ++nt) {
        int pix = nt * 16 + col;
        int n = b * HW + r0 * W56 + pix;
        unsigned int pkd = 0;
#pragma unroll
        for (int r = 0; r < 4; ++r) {
            int qv = requant_f(acc[nt][r], cm0, cP, cN, cT, czo);
            int a2 = (qv - czo) * bw[r] + bb[r];
            int q2 = requant_f(a2, bm0, bP, bN, bT, bzo);
            pkd |= ((unsigned int)((q2 - zin3) & 255)) << (8 * r);
        }
        *(unsigned int*)(t2 + (size_t)n * 64 + co0 + rowb) = pkd;
    }
}

// -------- conv3: 1x1 64->256 + bn3 + residual -> out. grid (784,4) ----------
__global__ __launch_bounds__(256, 4) void k_conv3(
    const signed char* __restrict__ t2, const v4i* __restrict__ wp3,
    const float* __restrict__ bn_w, const float* __restrict__ bn_b,
    const int* __restrict__ x,
    const int* __restrict__ conv_m0, const int* __restrict__ conv_shift,
    const int* __restrict__ conv_zout,
    const int* __restrict__ bn_m0, const int* __restrict__ bn_shift,
    const int* __restrict__ bn_zout,
    const int* __restrict__ add_z, const int* __restrict__ add_m0,
    const int* __restrict__ add_shift, const int* __restrict__ add_zout,
    int* __restrict__ out)
{
    __shared__ v4i sm[640];
    __shared__ int lutA[256], lutB[256];          // residual / branch rescale
    const int tid = threadIdx.x, lane = tid & 63, wv = tid >> 6;
    const int col = lane & 15, koff = lane >> 4;
    const int nbase = blockIdx.x * 128;
    const int co0 = blockIdx.y * 64 + wv * 16;
    const int rowb = koff * 4;

    v4i a = wp3[(blockIdx.y * 4 + wv) * 64 + lane];

    // build the two 256-entry combine LUTs (one entry per thread)
    {
        const int az0 = add_z[0], az1 = add_z[1];
        const int am0 = add_m0[0], am1 = add_m0[1];
        const int ash0 = add_shift[0], ash1 = add_shift[1];
        const int azout = add_zout[0];
        long long pA = (long long)(tid - az0) * am0;
        long long pB = (long long)(tid - az1) * am1;
        long long P0 = (1LL << 30) + (1LL << (30 + ash0));
        long long N0 = (1LL - (1LL << 30)) + (1LL << (30 + ash0));
        long long P1 = (1LL << 30) + (1LL << (30 + ash1));
        long long N1 = (1LL - (1LL << 30)) + (1LL << (30 + ash1));
        lutA[tid] = (int)((pA + (pA >= 0 ? P0 : N0)) >> (31 + ash0));
        lutB[tid] = (int)((pB + (pB >= 0 ? P1 : N1)) >> (31 + ash1)) + azout;
    }

    int nn[8], pb[8], phw[8];
#pragma unroll
    for (int nt = 0; nt < 8; ++nt) {
        nn[nt] = nbase + nt * 16 + col;
        pb[nt] = nn[nt] / HW;
        phw[nt] = nn[nt] - pb[nt] * HW;
    }
    int xv[8][4];
#pragma unroll
    for (int nt = 0; nt < 8; ++nt)
#pragma unroll
        for (int r = 0; r < 4; ++r)
            xv[nt][r] = x[((size_t)pb[nt] * CIN + co0 + rowb + r) * HW + phw[nt]];

    const v4i* t2v = (const v4i*)t2;
#pragma unroll
    for (int k = 0; k < 2; ++k) {
        int idx = tid + k * 256;
        int pixl = idx >> 2, part = idx & 3;
        sm[pixl * 5 + part] = t2v[(size_t)(nbase + pixl) * 4 + part];
    }
    __syncthreads();

    v4i acc[8];
#pragma unroll
    for (int i = 0; i < 8; ++i) acc[i] = (v4i){0, 0, 0, 0};
#pragma unroll
    for (int nt = 0; nt < 8; ++nt) {
        v4i bf = sm[(nt * 16 + col) * 5 + koff];
        acc[nt] = __builtin_amdgcn_mfma_i32_16x16x64_i8(a, bf, acc[nt], 0, 0, 0);
    }

    const int cm0 = conv_m0[2], csh = conv_shift[2], czo = conv_zout[2];
    const int bm0 = bn_m0[2], bsh = bn_shift[2], bzo = bn_zout[2];
    const long long cP = (1LL << 30) + (1LL << (30 + csh));
    const long long cN = (1LL - (1LL << 30)) + (1LL << (30 + csh));
    const long long bP = (1LL << 30) + (1LL << (30 + bsh));
    const long long bN = (1LL - (1LL << 30)) + (1LL << (30 + bsh));
    const int cT = 31 + csh, bT = 31 + bsh;
    int bw[4], bb[4];
#pragma unroll
    for (int r = 0; r < 4; ++r) {
        bw[r] = (int)bn_w[co0 + rowb + r];
        bb[r] = (int)bn_b[co0 + rowb + r];
    }
#pragma unroll
    for (int nt = 0; nt < 8; ++nt) {
#pragma unroll
        for (int r = 0; r < 4; ++r) {
            int qv = requant_f(acc[nt][r], cm0, cP, cN, cT, czo);
            int a2 = (qv - czo) * bw[r] + bb[r];
            int q2 = requant_f(a2, bm0, bP, bN, bT, bzo);
            int res = lutA[xv[nt][r]] + lutB[q2];
            res = res < 0 ? 0 : (res > 255 ? 255 : res);
            out[((size_t)pb[nt] * CIN + co0 + rowb + r) * HW + phw[nt]] = res;
        }
    }
}

extern "C" void kernel_launch(void* const* d_in, const int* in_sizes, int n_in,
                              void* d_out, int out_size, void* d_ws, size_t ws_size,
                              hipStream_t stream) {
    const int* x = (const int*)d_in[0];
    const float* w1 = (const float*)d_in[1];
    const float* w2 = (const float*)d_in[2];
    const float* w3 = (const float*)d_in[3];
    const float* bn1_w = (const float*)d_in[4];
    const float* bn1_b = (const float*)d_in[5];
    const float* bn2_w = (const float*)d_in[6];
    const float* bn2_b = (const float*)d_in[7];
    const float* bn3_w = (const float*)d_in[8];
    const float* bn3_b = (const float*)d_in[9];
    const int* conv_zin = (const int*)d_in[10];
    const int* conv_m0 = (const int*)d_in[11];
    const int* conv_shift = (const int*)d_in[12];
    const int* conv_zout = (const int*)d_in[13];
    const int* bn_m0 = (const int*)d_in[14];
    const int* bn_shift = (const int*)d_in[15];
    const int* bn_zout = (const int*)d_in[16];
    const int* add_z = (const int*)d_in[17];
    const int* add_m0 = (const int*)d_in[18];
    const int* add_shift = (const int*)d_in[19];
    const int* add_zout = (const int*)d_in[20];

    v4i* wp = (v4i*)d_ws;
    signed char* t1 = (signed char*)d_ws + WP_BYTES;
    signed char* t2 = t1 + T1_BYTES;

    const v4i* wp1 = wp;
    const v4i* wp2 = wp + 16 * 64;
    const v4i* wp3 = wp + 52 * 64;

    k_prep<<<dim3(17), dim3(256), 0, stream>>>(w1, w2, w3, wp);
    k_conv1<<<dim3(28, 32), dim3(256), 0, stream>>>(x, wp1, bn1_w, bn1_b,
        conv_zin, conv_m0, conv_shift, conv_zout, bn_m0, bn_shift, bn_zout, t1);
    k_conv2<<<dim3(14, 32), dim3(256), 0, stream>>>(t1, wp2, bn2_w, bn2_b,
        conv_zin, conv_m0, conv_shift, conv_zout, bn_m0, bn_shift, bn_zout, t2);
    k_conv3<<<dim3(784, 4), dim3(256), 0, stream>>>(t2, wp3, bn3_w, bn3_b,
        x, conv_m0, conv_shift, conv_zout, bn_m0, bn_shift, bn_zout,
        add_z, add_m0, add_shift, add_zout, (int*)d_out);
}

// Round 7
// 281.547 us; speedup vs baseline: 1.0078x; 1.0078x over previous
//
#include <hip/hip_runtime.h>

// QuantizedBottleneck, single fused kernel + weight-prep.
//   prep : pack all MFMA A-fragments (w1/w2/w3 -> i8) into d_ws
//   fused: per block = (batch b, 4 output rows r0..r0+3):
//     stage A: conv1 1x1 256->64 on 6-row halo (336 px) -> mid slab (LDS, i8)
//     stage B: conv2 3x3 64->64 from padded-col slab -> mid2 (LDS, i8)
//     stage C: conv3 1x1 64->256 + bn3 + residual add (LDS LUTs) -> out
// mid holds (q-zin2), mid2 holds (q-zin3): zero-padding == zero bytes.
// Requant via exact single-shift identity:
//   ((p+nudge)>>31 + 2^(s-1)) >> s == (p + nudge + 2^(30+s)) >> (31+s)
// MFMA 16x16x64_i8: A[m=lane&15][k=(lane>>4)*16+j], B[k][n=lane&15],
// C/D: col=lane&15, row=(lane>>4)*4+reg.   (no nontemporal builtins — R5 lesson)

typedef int v4i __attribute__((ext_vector_type(4)));

#define BATCH 32
#define CIN 256
#define CMID 64
#define HW 3136
#define W56 56
#define WP_BYTES ((size_t)68 * 64 * 16)

__device__ __forceinline__ int requant_f(int acc, int M0, long long pAdd,
                                         long long nAdd, int tSh, int zout) {
    long long prod = (long long)acc * (long long)M0;
    long long add = (prod >= 0) ? pAdd : nAdd;
    int v = (int)((prod + add) >> tSh) + zout;
    return v < 0 ? 0 : (v > 255 ? 255 : v);
}

__device__ __forceinline__ v4i pack16f(const float* src, int stride) {
    v4i r;
#pragma unroll
    for (int d = 0; d < 4; ++d) {
        unsigned int u = 0;
#pragma unroll
        for (int by = 0; by < 4; ++by) {
            int v = (int)src[(d * 4 + by) * stride];
            u |= ((unsigned int)(v & 255)) << (8 * by);
        }
        r[d] = (int)u;
    }
    return r;
}

// -------- prep: fragsets w1 [0,16), w2 [16,52), w3 [52,68) -------------------
__global__ __launch_bounds__(256) void k_prep(
    const float* __restrict__ w1, const float* __restrict__ w2,
    const float* __restrict__ w3, v4i* __restrict__ wp)
{
    int id = blockIdx.x * 256 + threadIdx.x;
    int fid = id >> 6, lane = id & 63;
    if (fid >= 68) return;
    int col = lane & 15, ci0 = (lane >> 4) * 16;
    const float* src;
    int stride;
    if (fid < 16) {
        int wv = fid >> 2, ks = fid & 3;
        src = w1 + (size_t)(wv * 16 + col) * 256 + ks * 64 + ci0;
        stride = 1;
    } else if (fid < 52) {
        int i = fid - 16, wv = i / 9, t = i - wv * 9;
        src = w2 + ((size_t)(wv * 16 + col) * 64 + ci0) * 9 + t;
        stride = 9;
    } else {
        int s = fid - 52;
        src = w3 + (size_t)(s * 16 + col) * 64 + ci0;
        stride = 1;
    }
    wp[fid * 64 + lane] = pack16f(src, stride);
}

// -------- fused bottleneck: grid (14, 32), block 256 ------------------------
__global__ __launch_bounds__(256, 2) void k_fused(
    const int* __restrict__ x, const v4i* __restrict__ wp,
    const float* __restrict__ bn1_w, const float* __restrict__ bn1_b,
    const float* __restrict__ bn2_w, const float* __restrict__ bn2_b,
    const float* __restrict__ bn3_w, const float* __restrict__ bn3_b,
    const int* __restrict__ conv_zin, const int* __restrict__ conv_m0,
    const int* __restrict__ conv_shift, const int* __restrict__ conv_zout,
    const int* __restrict__ bn_m0, const int* __restrict__ bn_shift,
    const int* __restrict__ bn_zout,
    const int* __restrict__ add_z, const int* __restrict__ add_m0,
    const int* __restrict__ add_shift, const int* __restrict__ add_zout,
    int* __restrict__ out)
{
    __shared__ v4i smX[1680];              // stage A: x-slab 336 px x 80B; stage C: mid2
    __shared__ v4i smM[1740];              // mid slab: 6 rows x 58 cols x 80B
    __shared__ int lutA[256], lutB[256];

    const int tid = threadIdx.x, lane = tid & 63, wv = tid >> 6;
    const int col = lane & 15, koff = lane >> 4;
    const int b = blockIdx.y, r0 = blockIdx.x * 4;
    const int rowb = koff * 4;
    const int co0 = wv * 16;

    // residual-combine LUTs (one entry per thread; covered by pre-stage-B barrier)
    {
        const int az0 = add_z[0], az1 = add_z[1];
        const int am0 = add_m0[0], am1 = add_m0[1];
        const int ash0 = add_shift[0], ash1 = add_shift[1];
        const int azout = add_zout[0];
        long long pA = (long long)(tid - az0) * am0;
        long long pB = (long long)(tid - az1) * am1;
        long long P0 = (1LL << 30) + (1LL << (30 + ash0));
        long long N0 = (1LL - (1LL << 30)) + (1LL << (30 + ash0));
        long long P1 = (1LL << 30) + (1LL << (30 + ash1));
        long long N1 = (1LL - (1LL << 30)) + (1LL << (30 + ash1));
        lutA[tid] = (int)((pA + (pA >= 0 ? P0 : N0)) >> (31 + ash0));
        lutB[tid] = (int)((pB + (pB >= 0 ? P1 : N1)) >> (31 + ash1)) + azout;
    }
    // zero mid-slab edge columns 0 and 57 (6 rows x 64 B)
    if (tid < 192) {
        int e = tid >> 4, d = tid & 15;
        int row = e >> 1, side = e & 1;
        ((int*)smM)[(row * 58 + side * 57) * 20 + d] = 0;
    }

    const int zin = conv_zin[0];
    v4i a1[4];
#pragma unroll
    for (int ks = 0; ks < 4; ++ks) a1[ks] = wp[(wv * 4 + ks) * 64 + lane];

    // ---------------- stage A: conv1 on 336 halo px, K=256 -----------------
    v4i accA[21];
#pragma unroll
    for (int i = 0; i < 21; ++i) accA[i] = (v4i){0, 0, 0, 0};

    unsigned long long* smuX = (unsigned long long*)smX;
    for (int ks = 0; ks < 4; ++ks) {
        if (ks) __syncthreads();               // prior MFMA reads of smX done
#pragma unroll
        for (int u = 0; u < 3; ++u) {
            int unit = tid + u * 256;
            if (unit < 672) {                  // 84 px-quads x 8 ci-groups
                int cg = unit & 7, qq = unit >> 3;
                int row = qq / 14, quad = qq - row * 14;
                int grow = r0 - 1 + row;
                v4i xa[8];
                if ((unsigned)grow < 56u) {
                    const int* xb = x + (size_t)(b * CIN + ks * 64 + cg * 8) * HW
                                      + grow * W56 + quad * 4;
#pragma unroll
                    for (int j = 0; j < 8; ++j)
                        xa[j] = *(const v4i*)(xb + (size_t)j * HW);
                } else {
#pragma unroll
                    for (int j = 0; j < 8; ++j) {
                        v4i z; z[0] = zin; z[1] = zin; z[2] = zin; z[3] = zin;
                        xa[j] = z;             // packs to 0 after -zin
                    }
                }
#pragma unroll
                for (int p = 0; p < 4; ++p) {
                    unsigned int lo = 0, hi = 0;
#pragma unroll
                    for (int j = 0; j < 4; ++j) {
                        lo |= ((unsigned int)((xa[j][p] - zin) & 255)) << (8 * j);
                        hi |= ((unsigned int)((xa[j + 4][p] - zin) & 255)) << (8 * j);
                    }
                    smuX[(qq * 4 + p) * 10 + cg] = ((unsigned long long)hi << 32) | lo;
                }
            }
        }
        __syncthreads();
#pragma unroll
        for (int nt = 0; nt < 21; ++nt) {
            v4i bf = smX[(nt * 16 + col) * 5 + koff];
            accA[nt] = __builtin_amdgcn_mfma_i32_16x16x64_i8(a1[ks], bf, accA[nt], 0, 0, 0);
        }
    }

    // stage A epilogue: requant + bn1 -> (q - zin2) bytes into padded mid slab
    {
        const int cm0 = conv_m0[0], csh = conv_shift[0], czo = conv_zout[0];
        const int bm0 = bn_m0[0], bsh = bn_shift[0], bzo = bn_zout[0];
        const long long cP = (1LL << 30) + (1LL << (30 + csh));
        const long long cN = (1LL - (1LL << 30)) + (1LL << (30 + csh));
        const long long bP = (1LL << 30) + (1LL << (30 + bsh));
        const long long bN = (1LL - (1LL << 30)) + (1LL << (30 + bsh));
        const int cT = 31 + csh, bT = 31 + bsh;
        const int zin2 = conv_zin[1];
        int bw[4], bb[4];
#pragma unroll
        for (int r = 0; r < 4; ++r) {
            bw[r] = (int)bn1_w[co0 + rowb + r];
            bb[r] = (int)bn1_b[co0 + rowb + r];
        }
#pragma unroll
        for (int nt = 0; nt < 21; ++nt) {
            int px = nt * 16 + col;
            int row = px / W56, gw = px - row * W56;
            int grow = r0 - 1 + row;
            unsigned int pkd = 0;
            if ((unsigned)grow < 56u) {
#pragma unroll
                for (int r = 0; r < 4; ++r) {
                    int q1 = requant_f(accA[nt][r], cm0, cP, cN, cT, czo);
                    int a2 = (q1 - czo) * bw[r] + bb[r];
                    int q2 = requant_f(a2, bm0, bP, bN, bT, bzo);
                    pkd |= ((unsigned int)((q2 - zin2) & 255)) << (8 * r);
                }
            }
            ((int*)smM)[(row * 58 + 1 + gw) * 20 + wv * 4 + koff] = (int)pkd;
        }
    }
    __syncthreads();

    // ---------------- stage B: conv2 3x3 from mid slab ----------------------
    v4i a2f[9];
#pragma unroll
    for (int t = 0; t < 9; ++t) a2f[t] = wp[(16 + wv * 9 + t) * 64 + lane];

    int basep[14];
#pragma unroll
    for (int nt = 0; nt < 14; ++nt) {
        int pix = nt * 16 + col;
        int orow = pix / W56, wc = pix - orow * W56;
        basep[nt] = (orow * 58 + wc) * 5 + koff;
    }

    v4i accB[14];
#pragma unroll
    for (int i = 0; i < 14; ++i) accB[i] = (v4i){0, 0, 0, 0};
#pragma unroll
    for (int kh = 0; kh < 3; ++kh) {
#pragma unroll
        for (int kw = 0; kw < 3; ++kw) {
            v4i af = a2f[kh * 3 + kw];
            const int toff = (kh * 58 + kw) * 5;
#pragma unroll
            for (int nt = 0; nt < 14; ++nt) {
                v4i bf = smM[basep[nt] + toff];
                accB[nt] = __builtin_amdgcn_mfma_i32_16x16x64_i8(af, bf, accB[nt], 0, 0, 0);
            }
        }
    }

    // stage B epilogue: requant + bn2 -> (q - zin3) bytes into mid2 (smX region)
    {
        const int cm0 = conv_m0[1], csh = conv_shift[1], czo = conv_zout[1];
        const int bm0 = bn_m0[1], bsh = bn_shift[1], bzo = bn_zout[1];
        const long long cP = (1LL << 30) + (1LL << (30 + csh));
        const long long cN = (1LL - (1LL << 30)) + (1LL << (30 + csh));
        const long long bP = (1LL << 30) + (1LL << (30 + bsh));
        const long long bN = (1LL - (1LL << 30)) + (1LL << (30 + bsh));
        const int cT = 31 + csh, bT = 31 + bsh;
        const int zin3 = conv_zin[2];
        int bw[4], bb[4];
#pragma unroll
        for (int r = 0; r < 4; ++r) {
            bw[r] = (int)bn2_w[co0 + rowb + r];
            bb[r] = (int)bn2_b[co0 + rowb + r];
        }
#pragma unroll
        for (int nt = 0; nt < 14; ++nt) {
            unsigned int pkd = 0;
#pragma unroll
            for (int r = 0; r < 4; ++r) {
                int q1 = requant_f(accB[nt][r], cm0, cP, cN, cT, czo);
                int a2 = (q1 - czo) * bw[r] + bb[r];
                int q2 = requant_f(a2, bm0, bP, bN, bT, bzo);
                pkd |= ((unsigned int)((q2 - zin3) & 255)) << (8 * r);
            }
            ((int*)smX)[(nt * 16 + col) * 20 + wv * 4 + koff] = (int)pkd;
        }
    }

    // preload tile-0 residual x (global, independent of LDS) before the barrier
    v4i a3f[4];
#pragma unroll
    for (int f = 0; f < 4; ++f) a3f[f] = wp[(52 + wv * 4 + f) * 64 + lane];
    const int ghw0 = r0 * W56;
    int xcur[4][4], xnxt[4][4];
#pragma unroll
    for (int f = 0; f < 4; ++f)
#pragma unroll
        for (int r = 0; r < 4; ++r)
            xcur[f][r] = x[(size_t)(b * CIN + wv * 64 + f * 16 + rowb + r) * HW + ghw0 + col];
    __syncthreads();

    // ---------------- stage C: conv3 1x1 64->256 + bn3 + residual -----------
    {
        const int cm0 = conv_m0[2], csh = conv_shift[2], czo = conv_zout[2];
        const int bm0 = bn_m0[2], bsh = bn_shift[2], bzo = bn_zout[2];
        const long long cP = (1LL << 30) + (1LL << (30 + csh));
        const long long cN = (1LL - (1LL << 30)) + (1LL << (30 + csh));
        const long long bP = (1LL << 30) + (1LL << (30 + bsh));
        const long long bN = (1LL - (1LL << 30)) + (1LL << (30 + bsh));
        const int cT = 31 + csh, bT = 31 + bsh;
        int bw[4][4], bb[4][4];
#pragma unroll
        for (int f = 0; f < 4; ++f)
#pragma unroll
            for (int r = 0; r < 4; ++r) {
                bw[f][r] = (int)bn3_w[wv * 64 + f * 16 + rowb + r];
                bb[f][r] = (int)bn3_b[wv * 64 + f * 16 + rowb + r];
            }
        const v4i zf = (v4i){0, 0, 0, 0};
#pragma unroll
        for (int nt = 0; nt < 14; ++nt) {
            if (nt < 13) {
#pragma unroll
                for (int f = 0; f < 4; ++f)
#pragma unroll
                    for (int r = 0; r < 4; ++r)
                        xnxt[f][r] = x[(size_t)(b * CIN + wv * 64 + f * 16 + rowb + r) * HW
                                       + ghw0 + (nt + 1) * 16 + col];
            }
            v4i bf = smX[(nt * 16 + col) * 5 + koff];
            v4i accC[4];
#pragma unroll
            for (int f = 0; f < 4; ++f)
                accC[f] = __builtin_amdgcn_mfma_i32_16x16x64_i8(a3f[f], bf, zf, 0, 0, 0);
#pragma unroll
            for (int f = 0; f < 4; ++f)
#pragma unroll
                for (int r = 0; r < 4; ++r) {
                    int q1 = requant_f(accC[f][r], cm0, cP, cN, cT, czo);
                    int a2 = (q1 - czo) * bw[f][r] + bb[f][r];
                    int q2 = requant_f(a2, bm0, bP, bN, bT, bzo);
                    int res = lutA[xcur[f][r]] + lutB[q2];
                    res = res < 0 ? 0 : (res > 255 ? 255 : res);
                    out[(size_t)(b * CIN + wv * 64 + f * 16 + rowb + r) * HW
                        + ghw0 + nt * 16 + col] = res;
                }
#pragma unroll
            for (int f = 0; f < 4; ++f)
#pragma unroll
                for (int r = 0; r < 4; ++r) xcur[f][r] = xnxt[f][r];
        }
    }
}

extern "C" void kernel_launch(void* const* d_in, const int* in_sizes, int n_in,
                              void* d_out, int out_size, void* d_ws, size_t ws_size,
                              hipStream_t stream) {
    const int* x = (const int*)d_in[0];
    const float* w1 = (const float*)d_in[1];
    const float* w2 = (const float*)d_in[2];
    const float* w3 = (const float*)d_in[3];
    const float* bn1_w = (const float*)d_in[4];
    const float* bn1_b = (const float*)d_in[5];
    const float* bn2_w = (const float*)d_in[6];
    const float* bn2_b = (const float*)d_in[7];
    const float* bn3_w = (const float*)d_in[8];
    const float* bn3_b = (const float*)d_in[9];
    const int* conv_zin = (const int*)d_in[10];
    const int* conv_m0 = (const int*)d_in[11];
    const int* conv_shift = (const int*)d_in[12];
    const int* conv_zout = (const int*)d_in[13];
    const int* bn_m0 = (const int*)d_in[14];
    const int* bn_shift = (const int*)d_in[15];
    const int* bn_zout = (const int*)d_in[16];
    const int* add_z = (const int*)d_in[17];
    const int* add_m0 = (const int*)d_in[18];
    const int* add_shift = (const int*)d_in[19];
    const int* add_zout = (const int*)d_in[20];

    v4i* wp = (v4i*)d_ws;

    k_prep<<<dim3(17), dim3(256), 0, stream>>>(w1, w2, w3, wp);
    k_fused<<<dim3(14, 32), dim3(256), 0, stream>>>(x, wp,
        bn1_w, bn1_b, bn2_w, bn2_b, bn3_w, bn3_b,
        conv_zin, conv_m0, conv_shift, conv_zout, bn_m0, bn_shift, bn_zout,
        add_z, add_m0, add_shift, add_zout, (int*)d_out);
}